// Round 1
// baseline (539.177 us; speedup 1.0000x reference)
//
#include <hip/hip_runtime.h>
#include <hip/hip_bf16.h>
#include <cmath>

typedef unsigned short u16;
typedef __attribute__((ext_vector_type(8))) short short8;
typedef __attribute__((ext_vector_type(4))) float float4v;
#define LN_EPS 1e-5f

__device__ __forceinline__ float us2f(u16 u) {
    return __uint_as_float(((unsigned int)u) << 16);
}
__device__ __forceinline__ u16 f2us(float f) {
    __hip_bfloat16 h = __float2bfloat16(f);
    return *(u16*)&h;
}

// Fast posenc: double-precision argument reduction (exact for pos<4096),
// then hardware v_sin_f32/v_cos_f32. Abs err ~1e-6 — well inside the
// ~2.4e-4 gap between exact posenc and the reference's own f32-rounded
// angle (the previously-passing double path had the same gap).
__device__ __forceinline__ float posenc_f(int s, int d) {
    const double c = -9.210340371976184 / 512.0;  // -ln(10000)/512
    double freq_rev = exp((double)(d & ~1) * c) * 0.15915494309189535;
    double rev = (double)s * freq_rev;
    float fr = (float)(rev - floor(rev));
    float ang = 6.28318530717958647692f * fr;
    return (d & 1) ? __cosf(ang) : __sinf(ang);
}

__global__ __launch_bounds__(256) void sentinel_kernel(float* out, float v) {
    out[blockIdx.x * 256 + threadIdx.x] = v;
}

// ---------------------------------------------------------------------------
// qkv9: MFMA bf16 hi/lo 3-product GEMM (X = E + posenc, W per z-panel).
// posenc via f64 arg-reduction + v_sin_f32 (no libm double trig).
// Epilogues identical to qkv8: Q f32 (d_out), K hi/lo bf16 planes,
// V transposed into [h][kb][col][rowlocal] tiles. grid (64 mb, 24 z).
// ---------------------------------------------------------------------------
__global__ __launch_bounds__(256) void qkv9_kernel(const float* __restrict__ E,
                                                   const float* __restrict__ Wq,
                                                   const float* __restrict__ Wk,
                                                   const float* __restrict__ Wv,
                                                   float* __restrict__ Qcat,
                                                   u16* __restrict__ Khi,
                                                   u16* __restrict__ Klo,
                                                   u16* __restrict__ Vt) {
    const int z = blockIdx.y;
    const int type = z >> 3, h = z & 7;
    const float* W = (type == 0 ? Wq : type == 1 ? Wk : Wv) + (long)h * 512 * 64;

    __shared__ u16 sAh[64][72], sAl[64][72];
    __shared__ u16 sBh[64][72], sBl[64][72];
    __shared__ double sFreqRev[512];

    const int t = threadIdx.x;
    const int w = t >> 6, l = t & 63;
    const int quad = l >> 4, l16 = l & 15;
    const int mw = w * 16;
    const int m0 = blockIdx.x * 64;

    {
        const double c = -9.210340371976184 / 512.0;  // -ln(10000)/512
        sFreqRev[t] = exp((double)(t & ~1) * c) * 0.15915494309189535;
        sFreqRev[t + 256] =
            exp((double)((t + 256) & ~1) * c) * 0.15915494309189535;
    }
    __syncthreads();

    const int ar = t >> 2, ac = (t & 3) << 4;   // A staging: row, 16-col base
    const double posd = (double)(m0 + ar);

    float4v acc[4];
    #pragma unroll
    for (int nt = 0; nt < 4; ++nt) acc[nt] = (float4v){0.f, 0.f, 0.f, 0.f};

    for (int k0 = 0; k0 < 512; k0 += 64) {
        // ---- stage A = X[m0+ar][k0+ac .. +15] split hi/lo
        #pragma unroll
        for (int u = 0; u < 4; ++u) {
            float4 ev = *(const float4*)(E + (long)(m0 + ar) * 512 + k0 + ac + 4 * u);
            float xs[4] = {ev.x, ev.y, ev.z, ev.w};
            ushort4 hh, ll;
            u16* hp = (u16*)&hh; u16* lp = (u16*)&ll;
            #pragma unroll
            for (int j = 0; j < 4; ++j) {
                const int col = k0 + ac + 4 * u + j;   // parity == j&1
                double rev = posd * sFreqRev[col];
                float fr = (float)(rev - floor(rev));
                float ang = 6.28318530717958647692f * fr;
                float pe = (j & 1) ? __cosf(ang) : __sinf(ang);
                float x = xs[j] + pe;
                u16 hi = f2us(x);
                hp[j] = hi;
                lp[j] = f2us(x - us2f(hi));
            }
            *(ushort4*)&sAh[ar][ac + 4 * u] = hh;
            *(ushort4*)&sAl[ar][ac + 4 * u] = ll;
        }
        // ---- stage B = W[k0..k0+63][0..63] transposed-split -> sB[n][k]
        {
            const int kr = t >> 2, nc = (t & 3) << 4;
            #pragma unroll
            for (int u = 0; u < 4; ++u) {
                float4 wv = *(const float4*)(W + (long)(k0 + kr) * 64 + nc + 4 * u);
                float ws4[4] = {wv.x, wv.y, wv.z, wv.w};
                #pragma unroll
                for (int j = 0; j < 4; ++j) {
                    const int n = nc + 4 * u + j;
                    u16 hi = f2us(ws4[j]);
                    sBh[n][kr] = hi;
                    sBl[n][kr] = f2us(ws4[j] - us2f(hi));
                }
            }
        }
        __syncthreads();
        #pragma unroll
        for (int kc = 0; kc < 2; ++kc) {
            short8 ah = *(const short8*)&sAh[mw + l16][kc * 32 + quad * 8];
            short8 al = *(const short8*)&sAl[mw + l16][kc * 32 + quad * 8];
            #pragma unroll
            for (int nt = 0; nt < 4; ++nt) {
                short8 bh = *(const short8*)&sBh[nt * 16 + l16][kc * 32 + quad * 8];
                short8 bl = *(const short8*)&sBl[nt * 16 + l16][kc * 32 + quad * 8];
                acc[nt] = __builtin_amdgcn_mfma_f32_16x16x32_bf16(ah, bh, acc[nt], 0, 0, 0);
                acc[nt] = __builtin_amdgcn_mfma_f32_16x16x32_bf16(ah, bl, acc[nt], 0, 0, 0);
                acc[nt] = __builtin_amdgcn_mfma_f32_16x16x32_bf16(al, bh, acc[nt], 0, 0, 0);
            }
        }
        __syncthreads();
    }

    if (type == 0) {
        #pragma unroll
        for (int nt = 0; nt < 4; ++nt)
            #pragma unroll
            for (int rr = 0; rr < 4; ++rr) {
                const int row = m0 + mw + quad * 4 + rr;
                Qcat[(long)row * 512 + h * 64 + nt * 16 + l16] = acc[nt][rr];
            }
    } else if (type == 1) {
        #pragma unroll
        for (int nt = 0; nt < 4; ++nt)
            #pragma unroll
            for (int rr = 0; rr < 4; ++rr) {
                const int row = m0 + mw + quad * 4 + rr;
                float v = acc[nt][rr];
                u16 hi = f2us(v);
                const long off = ((long)h * 4096 + row) * 64 + nt * 16 + l16;
                Khi[off] = hi;
                Klo[off] = f2us(v - us2f(hi));
            }
    } else {
        #pragma unroll
        for (int nt = 0; nt < 4; ++nt) {
            ushort4 o;
            o.x = f2us(acc[nt][0]); o.y = f2us(acc[nt][1]);
            o.z = f2us(acc[nt][2]); o.w = f2us(acc[nt][3]);
            const int col = nt * 16 + l16;
            *(ushort4*)(Vt + (((long)h * 64 + (m0 >> 6)) * 64 + col) * 64 +
                        (mw + quad * 4)) = o;
        }
    }
}

// ---------------------------------------------------------------------------
// flash8 (MFMA): unchanged. grid (64 qb, 8 h).
// ---------------------------------------------------------------------------
__global__ __launch_bounds__(256) void flash8_kernel(const u16* __restrict__ Khi,
                                                     const u16* __restrict__ Klo,
                                                     const u16* __restrict__ Vt,
                                                     float* __restrict__ QZ) {
    const int qb = blockIdx.x, h = blockIdx.y;

    __shared__ u16 sQh[64][72], sQl[64][72];
    __shared__ u16 sKh[64][72], sKl[64][72];
    __shared__ u16 sVt[64][72];
    __shared__ u16 sP[4][16][72];

    const int t = threadIdx.x;
    const int w = t >> 6;
    const int l = t & 63;
    const int quad = l >> 4;
    const int l16 = l & 15;
    const int mw = w * 16;

    {
        const int row = t >> 2, cc = (t & 3) << 4;
        #pragma unroll
        for (int u = 0; u < 4; ++u) {
            float4 q4 = *(const float4*)(QZ + (long)(qb * 64 + row) * 512 +
                                         h * 64 + cc + 4 * u);
            float qv[4] = {q4.x * 0.125f, q4.y * 0.125f,
                           q4.z * 0.125f, q4.w * 0.125f};
            ushort4 hh, ll;
            u16* hp = (u16*)&hh; u16* lp = (u16*)&ll;
            #pragma unroll
            for (int i = 0; i < 4; ++i) {
                u16 hi = f2us(qv[i]);
                hp[i] = hi;
                lp[i] = f2us(qv[i] - us2f(hi));
            }
            *(ushort4*)&sQh[row][cc + 4 * u] = hh;
            *(ushort4*)&sQl[row][cc + 4 * u] = ll;
        }
    }

    float m_i[4], l_i[4];
    float4v acc[4];
    #pragma unroll
    for (int r = 0; r < 4; ++r) { m_i[r] = -INFINITY; l_i[r] = 0.0f; }
    #pragma unroll
    for (int nt = 0; nt < 4; ++nt) acc[nt] = (float4v){0.f, 0.f, 0.f, 0.f};
    __syncthreads();

    for (int kb = 0; kb < 64; ++kb) {
        const int kr0 = kb * 64;
        {
            const int r = t >> 2, cc = (t & 3) << 4;
            const long koff = ((long)h * 4096 + kr0 + r) * 64 + cc;
            *(uint4*)&sKh[r][cc]     = *(const uint4*)(Khi + koff);
            *(uint4*)&sKh[r][cc + 8] = *(const uint4*)(Khi + koff + 8);
            *(uint4*)&sKl[r][cc]     = *(const uint4*)(Klo + koff);
            *(uint4*)&sKl[r][cc + 8] = *(const uint4*)(Klo + koff + 8);
            const long voff = (((long)h * 64 + kb) * 64 + r) * 64 + cc;
            *(uint4*)&sVt[r][cc]     = *(const uint4*)(Vt + voff);
            *(uint4*)&sVt[r][cc + 8] = *(const uint4*)(Vt + voff + 8);
        }
        __syncthreads();

        float4v s[4];
        #pragma unroll
        for (int nt = 0; nt < 4; ++nt) s[nt] = (float4v){0.f, 0.f, 0.f, 0.f};
        #pragma unroll
        for (int kc = 0; kc < 2; ++kc) {
            short8 aQh = *(const short8*)&sQh[mw + l16][kc * 32 + quad * 8];
            short8 aQl = *(const short8*)&sQl[mw + l16][kc * 32 + quad * 8];
            #pragma unroll
            for (int nt = 0; nt < 4; ++nt) {
                short8 bKh = *(const short8*)&sKh[nt * 16 + l16][kc * 32 + quad * 8];
                short8 bKl = *(const short8*)&sKl[nt * 16 + l16][kc * 32 + quad * 8];
                s[nt] = __builtin_amdgcn_mfma_f32_16x16x32_bf16(aQh, bKh, s[nt], 0, 0, 0);
                s[nt] = __builtin_amdgcn_mfma_f32_16x16x32_bf16(aQh, bKl, s[nt], 0, 0, 0);
                s[nt] = __builtin_amdgcn_mfma_f32_16x16x32_bf16(aQl, bKh, s[nt], 0, 0, 0);
            }
        }

        #pragma unroll
        for (int r = 0; r < 4; ++r) {
            float rm = fmaxf(fmaxf(s[0][r], s[1][r]), fmaxf(s[2][r], s[3][r]));
            rm = fmaxf(rm, __shfl_xor(rm, 1, 16));
            rm = fmaxf(rm, __shfl_xor(rm, 2, 16));
            rm = fmaxf(rm, __shfl_xor(rm, 4, 16));
            rm = fmaxf(rm, __shfl_xor(rm, 8, 16));
            const float nm = fmaxf(m_i[r], rm);
            const float al = __expf(m_i[r] - nm);
            float p0 = __expf(s[0][r] - nm);
            float p1 = __expf(s[1][r] - nm);
            float p2 = __expf(s[2][r] - nm);
            float p3 = __expf(s[3][r] - nm);
            float ps = p0 + p1 + p2 + p3;
            ps += __shfl_xor(ps, 1, 16);
            ps += __shfl_xor(ps, 2, 16);
            ps += __shfl_xor(ps, 4, 16);
            ps += __shfl_xor(ps, 8, 16);
            l_i[r] = l_i[r] * al + ps;
            m_i[r] = nm;
            acc[0][r] *= al; acc[1][r] *= al;
            acc[2][r] *= al; acc[3][r] *= al;
            const int pr = quad * 4 + r;
            sP[w][pr][0 * 16 + l16] = f2us(p0);
            sP[w][pr][1 * 16 + l16] = f2us(p1);
            sP[w][pr][2 * 16 + l16] = f2us(p2);
            sP[w][pr][3 * 16 + l16] = f2us(p3);
        }

        #pragma unroll
        for (int kc = 0; kc < 2; ++kc) {
            short8 aP = *(const short8*)&sP[w][l16][kc * 32 + quad * 8];
            #pragma unroll
            for (int nt = 0; nt < 4; ++nt) {
                short8 bV = *(const short8*)&sVt[nt * 16 + l16][kc * 32 + quad * 8];
                acc[nt] = __builtin_amdgcn_mfma_f32_16x16x32_bf16(aP, bV, acc[nt], 0, 0, 0);
            }
        }
        __syncthreads();
    }

    #pragma unroll
    for (int r = 0; r < 4; ++r) {
        const float inv = 1.0f / l_i[r];
        const int row = qb * 64 + mw + quad * 4 + r;
        #pragma unroll
        for (int nt = 0; nt < 4; ++nt)
            QZ[(long)row * 512 + h * 64 + nt * 16 + l16] = acc[nt][r] * inv;
    }
}

// ---------------------------------------------------------------------------
// wo2 (MFMA): tmp = Zcat @ WO via bf16 hi/lo 3-product.  grid (8 nb, 64 mb).
// ---------------------------------------------------------------------------
__global__ __launch_bounds__(256) void wo2_kernel(const float* __restrict__ A,
                                                  const float* __restrict__ B,
                                                  float* __restrict__ C) {
    __shared__ u16 sAh[64][72], sAl[64][72];
    __shared__ u16 sBh[64][72], sBl[64][72];
    const int t = threadIdx.x;
    const int w = t >> 6, l = t & 63;
    const int quad = l >> 4, l16 = l & 15;
    const int mw = w * 16;
    const int m0 = blockIdx.y * 64, n0 = blockIdx.x * 64;
    const int ar = t >> 2, ac = (t & 3) << 4;

    float4v acc[4];
    #pragma unroll
    for (int nt = 0; nt < 4; ++nt) acc[nt] = (float4v){0.f, 0.f, 0.f, 0.f};

    for (int k0 = 0; k0 < 512; k0 += 64) {
        #pragma unroll
        for (int u = 0; u < 4; ++u) {
            float4 av = *(const float4*)(A + (long)(m0 + ar) * 512 + k0 + ac + 4 * u);
            float xs[4] = {av.x, av.y, av.z, av.w};
            ushort4 hh, ll;
            u16* hp = (u16*)&hh; u16* lp = (u16*)&ll;
            #pragma unroll
            for (int j = 0; j < 4; ++j) {
                u16 hi = f2us(xs[j]);
                hp[j] = hi;
                lp[j] = f2us(xs[j] - us2f(hi));
            }
            *(ushort4*)&sAh[ar][ac + 4 * u] = hh;
            *(ushort4*)&sAl[ar][ac + 4 * u] = ll;
        }
        {
            const int kr = t >> 2, nc = (t & 3) << 4;
            #pragma unroll
            for (int u = 0; u < 4; ++u) {
                float4 wv = *(const float4*)(B + (long)(k0 + kr) * 512 + n0 + nc + 4 * u);
                float ws4[4] = {wv.x, wv.y, wv.z, wv.w};
                #pragma unroll
                for (int j = 0; j < 4; ++j) {
                    const int n = nc + 4 * u + j;
                    u16 hi = f2us(ws4[j]);
                    sBh[n][kr] = hi;
                    sBl[n][kr] = f2us(ws4[j] - us2f(hi));
                }
            }
        }
        __syncthreads();
        #pragma unroll
        for (int kc = 0; kc < 2; ++kc) {
            short8 ah = *(const short8*)&sAh[mw + l16][kc * 32 + quad * 8];
            short8 al = *(const short8*)&sAl[mw + l16][kc * 32 + quad * 8];
            #pragma unroll
            for (int nt = 0; nt < 4; ++nt) {
                short8 bh = *(const short8*)&sBh[nt * 16 + l16][kc * 32 + quad * 8];
                short8 bl = *(const short8*)&sBl[nt * 16 + l16][kc * 32 + quad * 8];
                acc[nt] = __builtin_amdgcn_mfma_f32_16x16x32_bf16(ah, bh, acc[nt], 0, 0, 0);
                acc[nt] = __builtin_amdgcn_mfma_f32_16x16x32_bf16(ah, bl, acc[nt], 0, 0, 0);
                acc[nt] = __builtin_amdgcn_mfma_f32_16x16x32_bf16(al, bh, acc[nt], 0, 0, 0);
            }
        }
        __syncthreads();
    }
    #pragma unroll
    for (int nt = 0; nt < 4; ++nt)
        #pragma unroll
        for (int rr = 0; rr < 4; ++rr) {
            const int row = m0 + mw + quad * 4 + rr;
            C[(long)row * 512 + n0 + nt * 16 + l16] = acc[nt][rr];
        }
}

// ---------------------------------------------------------------------------
// ln1: Z1 = LN(tmp + E + posenc)*g + be -> d_out f32 AND Z1b bf16 (ws).
// posenc via fast path (no libm double trig).
// ---------------------------------------------------------------------------
__global__ __launch_bounds__(256) void ln1_kernel(const float* __restrict__ tmp,
                                                  const float* __restrict__ E,
                                                  const float* __restrict__ g,
                                                  const float* __restrict__ be,
                                                  float* __restrict__ out,
                                                  u16* __restrict__ z1b) {
    const int r = blockIdx.x, t = threadIdx.x;
    const long base = (long)r * 512;
    __shared__ float red[256];

    float v0 = tmp[base + t] + E[base + t] + posenc_f(r, t);
    float v1 = tmp[base + t + 256] + E[base + t + 256] + posenc_f(r, t + 256);

    red[t] = v0 + v1; __syncthreads();
    for (int s2 = 128; s2 > 0; s2 >>= 1) {
        if (t < s2) red[t] += red[t + s2];
        __syncthreads();
    }
    const float mean = red[0] * (1.0f / 512.0f);
    __syncthreads();
    float d0 = v0 - mean, d1 = v1 - mean;
    red[t] = d0 * d0 + d1 * d1; __syncthreads();
    for (int s2 = 128; s2 > 0; s2 >>= 1) {
        if (t < s2) red[t] += red[t + s2];
        __syncthreads();
    }
    const float rs = rsqrtf(red[0] * (1.0f / 512.0f) + LN_EPS);
    float o0 = d0 * rs * g[t] + be[t];
    float o1 = d1 * rs * g[t + 256] + be[t + 256];
    out[base + t] = o0;
    out[base + t + 256] = o1;
    z1b[base + t] = f2us(o0);
    z1b[base + t + 256] = f2us(o1);
}

// ---------------------------------------------------------------------------
// wtrans: dst[n][k] (bf16) = src[k][n] (f32).  grid (K/64, N/64).
// ---------------------------------------------------------------------------
__global__ __launch_bounds__(256) void wtrans_kernel(const float* __restrict__ src,
                                                     u16* __restrict__ dst,
                                                     int K, int N) {
    __shared__ float sT[64][65];
    const int t = threadIdx.x;
    const int k0 = blockIdx.x * 64, n0 = blockIdx.y * 64;
    #pragma unroll
    for (int c = 0; c < 4; ++c) {
        const int r = (t >> 4) + c * 16;
        float4 v = *(const float4*)(src + (long)(k0 + r) * N + n0 + ((t & 15) << 2));
        sT[r][((t & 15) << 2) + 0] = v.x;
        sT[r][((t & 15) << 2) + 1] = v.y;
        sT[r][((t & 15) << 2) + 2] = v.z;
        sT[r][((t & 15) << 2) + 3] = v.w;
    }
    __syncthreads();
    const int n = t >> 2, kc = (t & 3) << 4;
    #pragma unroll
    for (int u = 0; u < 4; ++u) {
        ushort4 o;
        o.x = f2us(sT[kc + 4 * u + 0][n]);
        o.y = f2us(sT[kc + 4 * u + 1][n]);
        o.z = f2us(sT[kc + 4 * u + 2][n]);
        o.w = f2us(sT[kc + 4 * u + 3][n]);
        *(ushort4*)(dst + (long)(n0 + n) * K + k0 + kc + 4 * u) = o;
    }
}

// ---------------------------------------------------------------------------
// ffn1 (MFMA): Hff = relu(Z1b @ W1t^T + b1) -> bf16.
// ---------------------------------------------------------------------------
__global__ __launch_bounds__(256) void ffn1_kernel(const u16* __restrict__ A,
                                                   const u16* __restrict__ Bt,
                                                   const float* __restrict__ b1,
                                                   u16* __restrict__ C,
                                                   int m_base) {
    __shared__ u16 sA[64][72], sB[64][72];
    const int t = threadIdx.x;
    const int w = t >> 6, l = t & 63, quad = l >> 4, l16 = l & 15;
    const int mw = w * 16;
    const int m0 = m_base + blockIdx.y * 64, n0 = blockIdx.x * 64;
    const int r = t >> 2, cc = (t & 3) << 4;

    float4v acc[4];
    #pragma unroll
    for (int nt = 0; nt < 4; ++nt) acc[nt] = (float4v){0.f, 0.f, 0.f, 0.f};

    for (int kt = 0; kt < 512; kt += 64) {
        const long aoff = (long)(m0 + r) * 512 + kt + cc;
        *(uint4*)&sA[r][cc]     = *(const uint4*)(A + aoff);
        *(uint4*)&sA[r][cc + 8] = *(const uint4*)(A + aoff + 8);
        const long boff = (long)(n0 + r) * 512 + kt + cc;
        *(uint4*)&sB[r][cc]     = *(const uint4*)(Bt + boff);
        *(uint4*)&sB[r][cc + 8] = *(const uint4*)(Bt + boff + 8);
        __syncthreads();
        #pragma unroll
        for (int kc = 0; kc < 2; ++kc) {
            short8 a = *(const short8*)&sA[mw + l16][kc * 32 + quad * 8];
            #pragma unroll
            for (int nt = 0; nt < 4; ++nt) {
                short8 b = *(const short8*)&sB[nt * 16 + l16][kc * 32 + quad * 8];
                acc[nt] = __builtin_amdgcn_mfma_f32_16x16x32_bf16(a, b, acc[nt], 0, 0, 0);
            }
        }
        __syncthreads();
    }
    #pragma unroll
    for (int rr = 0; rr < 4; ++rr) {
        const int row = blockIdx.y * 64 + mw + quad * 4 + rr;  // chunk-local
        #pragma unroll
        for (int nt = 0; nt < 4; ++nt) {
            const int col = n0 + nt * 16 + l16;
            float v = acc[nt][rr] + b1[col];
            C[(long)row * 2048 + col] = f2us(fmaxf(v, 0.0f));
        }
    }
}

// ---------------------------------------------------------------------------
// ffn2 (MFMA): U = Hff @ W2t^T + b2 -> f32.
// ---------------------------------------------------------------------------
__global__ __launch_bounds__(256) void ffn2_kernel(const u16* __restrict__ A,
                                                   const u16* __restrict__ Bt,
                                                   const float* __restrict__ b2,
                                                   float* __restrict__ U) {
    __shared__ u16 sA[64][72], sB[64][72];
    const int t = threadIdx.x;
    const int w = t >> 6, l = t & 63, quad = l >> 4, l16 = l & 15;
    const int mw = w * 16;
    const int m0 = blockIdx.y * 64, n0 = blockIdx.x * 64;
    const int r = t >> 2, cc = (t & 3) << 4;

    float4v acc[4];
    #pragma unroll
    for (int nt = 0; nt < 4; ++nt) acc[nt] = (float4v){0.f, 0.f, 0.f, 0.f};

    for (int kt = 0; kt < 2048; kt += 64) {
        const long aoff = (long)(m0 + r) * 2048 + kt + cc;
        *(uint4*)&sA[r][cc]     = *(const uint4*)(A + aoff);
        *(uint4*)&sA[r][cc + 8] = *(const uint4*)(A + aoff + 8);
        const long boff = (long)(n0 + r) * 2048 + kt + cc;
        *(uint4*)&sB[r][cc]     = *(const uint4*)(Bt + boff);
        *(uint4*)&sB[r][cc + 8] = *(const uint4*)(Bt + boff + 8);
        __syncthreads();
        #pragma unroll
        for (int kc = 0; kc < 2; ++kc) {
            short8 a = *(const short8*)&sA[mw + l16][kc * 32 + quad * 8];
            #pragma unroll
            for (int nt = 0; nt < 4; ++nt) {
                short8 b = *(const short8*)&sB[nt * 16 + l16][kc * 32 + quad * 8];
                acc[nt] = __builtin_amdgcn_mfma_f32_16x16x32_bf16(a, b, acc[nt], 0, 0, 0);
            }
        }
        __syncthreads();
    }
    #pragma unroll
    for (int rr = 0; rr < 4; ++rr) {
        const int row = m0 + mw + quad * 4 + rr;
        #pragma unroll
        for (int nt = 0; nt < 4; ++nt) {
            const int col = n0 + nt * 16 + l16;
            U[(long)row * 512 + col] = acc[nt][rr] + b2[col];
        }
    }
}

// ---------------------------------------------------------------------------
// ln2: out = LN(U + Z1)*g + be (in place over Z1 rows).
// ---------------------------------------------------------------------------
__global__ __launch_bounds__(256) void ln2_kernel(const float* __restrict__ U,
                                                  const float* __restrict__ Z1,
                                                  const float* __restrict__ g,
                                                  const float* __restrict__ be,
                                                  float* __restrict__ out) {
    const int r = blockIdx.x, t = threadIdx.x;
    const long base = (long)r * 512;
    __shared__ float red[256];

    float v0 = U[base + t] + Z1[base + t];
    float v1 = U[base + t + 256] + Z1[base + t + 256];

    red[t] = v0 + v1; __syncthreads();
    for (int s2 = 128; s2 > 0; s2 >>= 1) {
        if (t < s2) red[t] += red[t + s2];
        __syncthreads();
    }
    const float mean = red[0] * (1.0f / 512.0f);
    __syncthreads();
    float d0 = v0 - mean, d1 = v1 - mean;
    red[t] = d0 * d0 + d1 * d1; __syncthreads();
    for (int s2 = 128; s2 > 0; s2 >>= 1) {
        if (t < s2) red[t] += red[t + s2];
        __syncthreads();
    }
    const float rs = rsqrtf(red[0] * (1.0f / 512.0f) + LN_EPS);
    out[base + t] = d0 * rs * g[t] + be[t];
    out[base + t + 256] = d1 * rs * g[t + 256] + be[t + 256];
}

// ---------------------------------------------------------------------------
// ws timeline (max 14 MB):
//   attention: Khi @0 (4) | Klo @4 (4) | Vt @8 (4)
//   wo/ln1:    tmp @0 (8) | Z1b @8 (4)
//   FFN:       W1t @0 (2) | W2t @2 (2) | Hff @4 (4/chunk) | U @12 (2/chunk)
// d_out: Qcat -> Zcat -> Z1 -> out (race-free phase overwrites).
// ---------------------------------------------------------------------------
extern "C" void kernel_launch(void* const* d_in, const int* in_sizes, int n_in,
                              void* d_out, int out_size, void* d_ws, size_t ws_size,
                              hipStream_t stream) {
    float* outf = (float*)d_out;

    static const int exp_sizes[13] = {2097152, 262144, 262144, 262144, 262144,
                                      1048576, 2048, 1048576, 512, 512, 512,
                                      512, 512};
    bool ok = (n_in == 13) && (out_size == 2097152) &&
              (ws_size >= (14ull << 20));
    if (ok) for (int i = 0; i < 13; ++i) if (in_sizes[i] != exp_sizes[i]) ok = false;
    if (!ok) { sentinel_kernel<<<16, 256, 0, stream>>>(outf, 1000.0f); return; }

    const float* E   = (const float*)d_in[0];
    const float* Wq  = (const float*)d_in[1];
    const float* Wk  = (const float*)d_in[2];
    const float* Wv  = (const float*)d_in[3];
    const float* WO  = (const float*)d_in[4];
    const float* W1  = (const float*)d_in[5];
    const float* b1  = (const float*)d_in[6];
    const float* W2  = (const float*)d_in[7];
    const float* b2  = (const float*)d_in[8];
    const float* g1  = (const float*)d_in[9];
    const float* be1 = (const float*)d_in[10];
    const float* g2  = (const float*)d_in[11];
    const float* be2 = (const float*)d_in[12];

    char* base = (char*)d_ws;
    u16*   Khi = (u16*)base;                    // 4 MB
    u16*   Klo = (u16*)(base + (4l << 20));     // 4 MB
    u16*   Vt  = (u16*)(base + (8l << 20));     // 4 MB
    float* tmp = (float*)base;                  // 8 MB (K dead)
    u16*   Z1b = (u16*)(base + (8l << 20));     // 4 MB (Vt dead)
    u16*   W1t = (u16*)base;                    // 2 MB (tmp dead)
    u16*   W2t = (u16*)(base + (2l << 20));     // 2 MB
    u16*   Hff = (u16*)(base + (4l << 20));     // 4 MB / chunk
    float* U   = (float*)(base + (12l << 20));  // 2 MB / chunk

    qkv9_kernel<<<dim3(64, 24), 256, 0, stream>>>(E, Wq, Wk, Wv, outf,
                                                  Khi, Klo, Vt);
    flash8_kernel<<<dim3(64, 8), 256, 0, stream>>>(Khi, Klo, Vt, outf);
    wo2_kernel<<<dim3(8, 64), 256, 0, stream>>>(outf, WO, tmp);
    ln1_kernel<<<4096, 256, 0, stream>>>(tmp, E, g1, be1, outf, Z1b);
    wtrans_kernel<<<dim3(8, 32), 256, 0, stream>>>(W1, W1t, 512, 2048);
    wtrans_kernel<<<dim3(32, 8), 256, 0, stream>>>(W2, W2t, 2048, 512);

    for (int c = 0; c < 4; ++c) {
        ffn1_kernel<<<dim3(32, 16), 256, 0, stream>>>(Z1b, W1t, b1, Hff,
                                                      c * 1024);
        ffn2_kernel<<<dim3(8, 16), 256, 0, stream>>>(Hff, W2t, b2, U);
        ln2_kernel<<<1024, 256, 0, stream>>>(U, outf + (long)c * 1024 * 512,
                                             g2, be2,
                                             outf + (long)c * 1024 * 512);
    }
}

// Round 2
// 472.763 us; speedup vs baseline: 1.1405x; 1.1405x over previous
//
#include <hip/hip_runtime.h>
#include <hip/hip_bf16.h>
#include <cmath>

typedef unsigned short u16;
typedef __attribute__((ext_vector_type(8))) short short8;
typedef __attribute__((ext_vector_type(4))) float float4v;
#define LN_EPS 1e-5f

__device__ __forceinline__ float us2f(u16 u) {
    return __uint_as_float(((unsigned int)u) << 16);
}
__device__ __forceinline__ u16 f2us(float f) {
    __hip_bfloat16 h = __float2bfloat16(f);
    return *(u16*)&h;
}

// Fast posenc: double-precision argument reduction (exact for pos<4096),
// then hardware v_sin_f32/v_cos_f32.
__device__ __forceinline__ float posenc_f(int s, int d) {
    const double c = -9.210340371976184 / 512.0;  // -ln(10000)/512
    double freq_rev = exp((double)(d & ~1) * c) * 0.15915494309189535;
    double rev = (double)s * freq_rev;
    float fr = (float)(rev - floor(rev));
    float ang = 6.28318530717958647692f * fr;
    return (d & 1) ? __cosf(ang) : __sinf(ang);
}

__global__ __launch_bounds__(256) void sentinel_kernel(float* out, float v) {
    out[blockIdx.x * 256 + threadIdx.x] = v;
}

// ---------------------------------------------------------------------------
// qkv9: MFMA bf16 hi/lo 3-product GEMM (X = E + posenc, W per z-panel).
// grid (64 mb, 24 z).
// ---------------------------------------------------------------------------
__global__ __launch_bounds__(256) void qkv9_kernel(const float* __restrict__ E,
                                                   const float* __restrict__ Wq,
                                                   const float* __restrict__ Wk,
                                                   const float* __restrict__ Wv,
                                                   float* __restrict__ Qcat,
                                                   u16* __restrict__ Khi,
                                                   u16* __restrict__ Klo,
                                                   u16* __restrict__ Vt) {
    const int z = blockIdx.y;
    const int type = z >> 3, h = z & 7;
    const float* W = (type == 0 ? Wq : type == 1 ? Wk : Wv) + (long)h * 512 * 64;

    __shared__ u16 sAh[64][72], sAl[64][72];
    __shared__ u16 sBh[64][72], sBl[64][72];
    __shared__ double sFreqRev[512];

    const int t = threadIdx.x;
    const int w = t >> 6, l = t & 63;
    const int quad = l >> 4, l16 = l & 15;
    const int mw = w * 16;
    const int m0 = blockIdx.x * 64;

    {
        const double c = -9.210340371976184 / 512.0;  // -ln(10000)/512
        sFreqRev[t] = exp((double)(t & ~1) * c) * 0.15915494309189535;
        sFreqRev[t + 256] =
            exp((double)((t + 256) & ~1) * c) * 0.15915494309189535;
    }
    __syncthreads();

    const int ar = t >> 2, ac = (t & 3) << 4;   // A staging: row, 16-col base
    const double posd = (double)(m0 + ar);

    float4v acc[4];
    #pragma unroll
    for (int nt = 0; nt < 4; ++nt) acc[nt] = (float4v){0.f, 0.f, 0.f, 0.f};

    for (int k0 = 0; k0 < 512; k0 += 64) {
        // ---- stage A = X[m0+ar][k0+ac .. +15] split hi/lo
        #pragma unroll
        for (int u = 0; u < 4; ++u) {
            float4 ev = *(const float4*)(E + (long)(m0 + ar) * 512 + k0 + ac + 4 * u);
            float xs[4] = {ev.x, ev.y, ev.z, ev.w};
            ushort4 hh, ll;
            u16* hp = (u16*)&hh; u16* lp = (u16*)&ll;
            #pragma unroll
            for (int j = 0; j < 4; ++j) {
                const int col = k0 + ac + 4 * u + j;   // parity == j&1
                double rev = posd * sFreqRev[col];
                float fr = (float)(rev - floor(rev));
                float ang = 6.28318530717958647692f * fr;
                float pe = (j & 1) ? __cosf(ang) : __sinf(ang);
                float x = xs[j] + pe;
                u16 hi = f2us(x);
                hp[j] = hi;
                lp[j] = f2us(x - us2f(hi));
            }
            *(ushort4*)&sAh[ar][ac + 4 * u] = hh;
            *(ushort4*)&sAl[ar][ac + 4 * u] = ll;
        }
        // ---- stage B = W[k0..k0+63][0..63] transposed-split -> sB[n][k]
        {
            const int kr = t >> 2, nc = (t & 3) << 4;
            #pragma unroll
            for (int u = 0; u < 4; ++u) {
                float4 wv = *(const float4*)(W + (long)(k0 + kr) * 64 + nc + 4 * u);
                float ws4[4] = {wv.x, wv.y, wv.z, wv.w};
                #pragma unroll
                for (int j = 0; j < 4; ++j) {
                    const int n = nc + 4 * u + j;
                    u16 hi = f2us(ws4[j]);
                    sBh[n][kr] = hi;
                    sBl[n][kr] = f2us(ws4[j] - us2f(hi));
                }
            }
        }
        __syncthreads();
        #pragma unroll
        for (int kc = 0; kc < 2; ++kc) {
            short8 ah = *(const short8*)&sAh[mw + l16][kc * 32 + quad * 8];
            short8 al = *(const short8*)&sAl[mw + l16][kc * 32 + quad * 8];
            #pragma unroll
            for (int nt = 0; nt < 4; ++nt) {
                short8 bh = *(const short8*)&sBh[nt * 16 + l16][kc * 32 + quad * 8];
                short8 bl = *(const short8*)&sBl[nt * 16 + l16][kc * 32 + quad * 8];
                acc[nt] = __builtin_amdgcn_mfma_f32_16x16x32_bf16(ah, bh, acc[nt], 0, 0, 0);
                acc[nt] = __builtin_amdgcn_mfma_f32_16x16x32_bf16(ah, bl, acc[nt], 0, 0, 0);
                acc[nt] = __builtin_amdgcn_mfma_f32_16x16x32_bf16(al, bh, acc[nt], 0, 0, 0);
            }
        }
        __syncthreads();
    }

    if (type == 0) {
        #pragma unroll
        for (int nt = 0; nt < 4; ++nt)
            #pragma unroll
            for (int rr = 0; rr < 4; ++rr) {
                const int row = m0 + mw + quad * 4 + rr;
                Qcat[(long)row * 512 + h * 64 + nt * 16 + l16] = acc[nt][rr];
            }
    } else if (type == 1) {
        #pragma unroll
        for (int nt = 0; nt < 4; ++nt)
            #pragma unroll
            for (int rr = 0; rr < 4; ++rr) {
                const int row = m0 + mw + quad * 4 + rr;
                float v = acc[nt][rr];
                u16 hi = f2us(v);
                const long off = ((long)h * 4096 + row) * 64 + nt * 16 + l16;
                Khi[off] = hi;
                Klo[off] = f2us(v - us2f(hi));
            }
    } else {
        #pragma unroll
        for (int nt = 0; nt < 4; ++nt) {
            ushort4 o;
            o.x = f2us(acc[nt][0]); o.y = f2us(acc[nt][1]);
            o.z = f2us(acc[nt][2]); o.w = f2us(acc[nt][3]);
            const int col = nt * 16 + l16;
            *(ushort4*)(Vt + (((long)h * 64 + (m0 >> 6)) * 64 + col) * 64 +
                        (mw + quad * 4)) = o;
        }
    }
}

// ---------------------------------------------------------------------------
// flash9 (MFMA, swapped-operand): Q in registers, K/V double-buffered with
// issue-early/write-late reg staging, one barrier per kb.
// QK^T computed as mfma(K,Q) -> S^T: each lane owns one q-row (q = mw+l16),
// softmax reduce = in-lane + 2 shfl. P packed to bf16 ushort4, conflict-free
// ds_write_b64. PV computed as mfma(V^T,P) -> O^T. grid (64 qb, 8 h).
// ---------------------------------------------------------------------------
__global__ __launch_bounds__(256) void flash9_kernel(const u16* __restrict__ Khi,
                                                     const u16* __restrict__ Klo,
                                                     const u16* __restrict__ Vt,
                                                     float* __restrict__ QZ) {
    const int qb = blockIdx.x, h = blockIdx.y;

    __shared__ u16 sKh[2][64][72], sKl[2][64][72], sVt[2][64][72];
    __shared__ u16 sP[4][16][72];

    const int t = threadIdx.x;
    const int w = t >> 6;
    const int l = t & 63;
    const int quad = l >> 4;
    const int l16 = l & 15;
    const int mw = w * 16;

    // ---- Q fragments in registers (x0.125, hi/lo split)
    short8 qh[2], ql[2];
    #pragma unroll
    for (int kc = 0; kc < 2; ++kc) {
        const float* qp = QZ + (long)(qb * 64 + mw + l16) * 512 + h * 64 +
                          kc * 32 + quad * 8;
        float4 qa = *(const float4*)qp;
        float4 qb4 = *(const float4*)(qp + 4);
        float qv[8] = {qa.x, qa.y, qa.z, qa.w, qb4.x, qb4.y, qb4.z, qb4.w};
        #pragma unroll
        for (int i = 0; i < 8; ++i) {
            float f = qv[i] * 0.125f;
            u16 hi = f2us(f);
            qh[kc][i] = (short)hi;
            ql[kc][i] = (short)f2us(f - us2f(hi));
        }
    }

    const int r = t >> 2, cc = (t & 3) << 4;
    const long sbase = (long)h * 262144 + (long)r * 64 + cc;

    uint4 rh0, rh1, rl0, rl1, rv0, rv1;
#define LOADKV(kb_) { const long o_ = sbase + (long)(kb_) * 4096;              \
        rh0 = *(const uint4*)(Khi + o_); rh1 = *(const uint4*)(Khi + o_ + 8);  \
        rl0 = *(const uint4*)(Klo + o_); rl1 = *(const uint4*)(Klo + o_ + 8);  \
        rv0 = *(const uint4*)(Vt + o_);  rv1 = *(const uint4*)(Vt + o_ + 8); }
#define STOREKV(b_) {                                                          \
        *(uint4*)&sKh[b_][r][cc] = rh0; *(uint4*)&sKh[b_][r][cc + 8] = rh1;    \
        *(uint4*)&sKl[b_][r][cc] = rl0; *(uint4*)&sKl[b_][r][cc + 8] = rl1;    \
        *(uint4*)&sVt[b_][r][cc] = rv0; *(uint4*)&sVt[b_][r][cc + 8] = rv1; }

    float m_i = -INFINITY, l_i = 0.0f;
    float4v acc[4];
    #pragma unroll
    for (int nt = 0; nt < 4; ++nt) acc[nt] = (float4v){0.f, 0.f, 0.f, 0.f};

    LOADKV(0);
    STOREKV(0);
    __syncthreads();

    for (int kb = 0; kb < 64; ++kb) {
        const int cur = kb & 1;
        if (kb < 63) LOADKV(kb + 1);   // issue next tile early (T14)

        // ---- QK^T swapped: s[nt] = S^T tile, lane owns q-row mw+l16
        float4v s[4];
        #pragma unroll
        for (int nt = 0; nt < 4; ++nt) s[nt] = (float4v){0.f, 0.f, 0.f, 0.f};
        __builtin_amdgcn_s_setprio(1);
        #pragma unroll
        for (int kc = 0; kc < 2; ++kc) {
            #pragma unroll
            for (int nt = 0; nt < 4; ++nt) {
                short8 bKh = *(const short8*)&sKh[cur][nt * 16 + l16][kc * 32 + quad * 8];
                short8 bKl = *(const short8*)&sKl[cur][nt * 16 + l16][kc * 32 + quad * 8];
                s[nt] = __builtin_amdgcn_mfma_f32_16x16x32_bf16(bKh, qh[kc], s[nt], 0, 0, 0);
                s[nt] = __builtin_amdgcn_mfma_f32_16x16x32_bf16(bKh, ql[kc], s[nt], 0, 0, 0);
                s[nt] = __builtin_amdgcn_mfma_f32_16x16x32_bf16(bKl, qh[kc], s[nt], 0, 0, 0);
            }
        }
        __builtin_amdgcn_s_setprio(0);

        // ---- online softmax: in-lane over 16 values + cross-quad (2 shfl)
        float rm = s[0][0];
        #pragma unroll
        for (int nt = 0; nt < 4; ++nt)
            #pragma unroll
            for (int rr = 0; rr < 4; ++rr) rm = fmaxf(rm, s[nt][rr]);
        rm = fmaxf(rm, __shfl_xor(rm, 16, 64));
        rm = fmaxf(rm, __shfl_xor(rm, 32, 64));
        const float nm = fmaxf(m_i, rm);
        const float al = __expf(m_i - nm);
        float p[4][4];
        float ps = 0.0f;
        #pragma unroll
        for (int nt = 0; nt < 4; ++nt)
            #pragma unroll
            for (int rr = 0; rr < 4; ++rr) {
                p[nt][rr] = __expf(s[nt][rr] - nm);
                ps += p[nt][rr];
            }
        ps += __shfl_xor(ps, 16, 64);
        ps += __shfl_xor(ps, 32, 64);
        l_i = l_i * al + ps;
        m_i = nm;
        #pragma unroll
        for (int nt = 0; nt < 4; ++nt) {
            acc[nt][0] *= al; acc[nt][1] *= al;
            acc[nt][2] *= al; acc[nt][3] *= al;
        }
        // ---- P -> LDS: lane writes keys nt*16+quad*4..+3 for its q-row
        #pragma unroll
        for (int nt = 0; nt < 4; ++nt) {
            ushort4 pk;
            pk.x = f2us(p[nt][0]); pk.y = f2us(p[nt][1]);
            pk.z = f2us(p[nt][2]); pk.w = f2us(p[nt][3]);
            *(ushort4*)&sP[w][l16][nt * 16 + quad * 4] = pk;
        }

        // ---- PV swapped: acc[nt] += mfma(V^T, P) -> O^T
        __builtin_amdgcn_s_setprio(1);
        #pragma unroll
        for (int kc = 0; kc < 2; ++kc) {
            short8 aP = *(const short8*)&sP[w][l16][kc * 32 + quad * 8];
            #pragma unroll
            for (int nt = 0; nt < 4; ++nt) {
                short8 bV = *(const short8*)&sVt[cur][nt * 16 + l16][kc * 32 + quad * 8];
                acc[nt] = __builtin_amdgcn_mfma_f32_16x16x32_bf16(bV, aP, acc[nt], 0, 0, 0);
            }
        }
        __builtin_amdgcn_s_setprio(0);

        if (kb < 63) STOREKV(cur ^ 1);   // write-late into alternate buffer
        __syncthreads();
    }
#undef LOADKV
#undef STOREKV

    // ---- epilogue: acc[nt][rr] = O[q=mw+l16][v=nt*16+quad*4+rr]
    const float inv = 1.0f / l_i;
    #pragma unroll
    for (int nt = 0; nt < 4; ++nt) {
        float4 o = make_float4(acc[nt][0] * inv, acc[nt][1] * inv,
                               acc[nt][2] * inv, acc[nt][3] * inv);
        *(float4*)(QZ + (long)(qb * 64 + mw + l16) * 512 + h * 64 +
                   nt * 16 + quad * 4) = o;
    }
}

// ---------------------------------------------------------------------------
// wo2 (MFMA): tmp = Zcat @ WO via bf16 hi/lo 3-product.  grid (8 nb, 64 mb).
// ---------------------------------------------------------------------------
__global__ __launch_bounds__(256) void wo2_kernel(const float* __restrict__ A,
                                                  const float* __restrict__ B,
                                                  float* __restrict__ C) {
    __shared__ u16 sAh[64][72], sAl[64][72];
    __shared__ u16 sBh[64][72], sBl[64][72];
    const int t = threadIdx.x;
    const int w = t >> 6, l = t & 63;
    const int quad = l >> 4, l16 = l & 15;
    const int mw = w * 16;
    const int m0 = blockIdx.y * 64, n0 = blockIdx.x * 64;
    const int ar = t >> 2, ac = (t & 3) << 4;

    float4v acc[4];
    #pragma unroll
    for (int nt = 0; nt < 4; ++nt) acc[nt] = (float4v){0.f, 0.f, 0.f, 0.f};

    for (int k0 = 0; k0 < 512; k0 += 64) {
        #pragma unroll
        for (int u = 0; u < 4; ++u) {
            float4 av = *(const float4*)(A + (long)(m0 + ar) * 512 + k0 + ac + 4 * u);
            float xs[4] = {av.x, av.y, av.z, av.w};
            ushort4 hh, ll;
            u16* hp = (u16*)&hh; u16* lp = (u16*)&ll;
            #pragma unroll
            for (int j = 0; j < 4; ++j) {
                u16 hi = f2us(xs[j]);
                hp[j] = hi;
                lp[j] = f2us(xs[j] - us2f(hi));
            }
            *(ushort4*)&sAh[ar][ac + 4 * u] = hh;
            *(ushort4*)&sAl[ar][ac + 4 * u] = ll;
        }
        {
            const int kr = t >> 2, nc = (t & 3) << 4;
            #pragma unroll
            for (int u = 0; u < 4; ++u) {
                float4 wv = *(const float4*)(B + (long)(k0 + kr) * 512 + n0 + nc + 4 * u);
                float ws4[4] = {wv.x, wv.y, wv.z, wv.w};
                #pragma unroll
                for (int j = 0; j < 4; ++j) {
                    const int n = nc + 4 * u + j;
                    u16 hi = f2us(ws4[j]);
                    sBh[n][kr] = hi;
                    sBl[n][kr] = f2us(ws4[j] - us2f(hi));
                }
            }
        }
        __syncthreads();
        #pragma unroll
        for (int kc = 0; kc < 2; ++kc) {
            short8 ah = *(const short8*)&sAh[mw + l16][kc * 32 + quad * 8];
            short8 al = *(const short8*)&sAl[mw + l16][kc * 32 + quad * 8];
            #pragma unroll
            for (int nt = 0; nt < 4; ++nt) {
                short8 bh = *(const short8*)&sBh[nt * 16 + l16][kc * 32 + quad * 8];
                short8 bl = *(const short8*)&sBl[nt * 16 + l16][kc * 32 + quad * 8];
                acc[nt] = __builtin_amdgcn_mfma_f32_16x16x32_bf16(ah, bh, acc[nt], 0, 0, 0);
                acc[nt] = __builtin_amdgcn_mfma_f32_16x16x32_bf16(ah, bl, acc[nt], 0, 0, 0);
                acc[nt] = __builtin_amdgcn_mfma_f32_16x16x32_bf16(al, bh, acc[nt], 0, 0, 0);
            }
        }
        __syncthreads();
    }
    #pragma unroll
    for (int nt = 0; nt < 4; ++nt)
        #pragma unroll
        for (int rr = 0; rr < 4; ++rr) {
            const int row = m0 + mw + quad * 4 + rr;
            C[(long)row * 512 + n0 + nt * 16 + l16] = acc[nt][rr];
        }
}

// ---------------------------------------------------------------------------
// ln1: Z1 = LN(tmp + E + posenc)*g + be -> d_out f32 AND Z1b bf16 (ws).
// ---------------------------------------------------------------------------
__global__ __launch_bounds__(256) void ln1_kernel(const float* __restrict__ tmp,
                                                  const float* __restrict__ E,
                                                  const float* __restrict__ g,
                                                  const float* __restrict__ be,
                                                  float* __restrict__ out,
                                                  u16* __restrict__ z1b) {
    const int r = blockIdx.x, t = threadIdx.x;
    const long base = (long)r * 512;
    __shared__ float red[256];

    float v0 = tmp[base + t] + E[base + t] + posenc_f(r, t);
    float v1 = tmp[base + t + 256] + E[base + t + 256] + posenc_f(r, t + 256);

    red[t] = v0 + v1; __syncthreads();
    for (int s2 = 128; s2 > 0; s2 >>= 1) {
        if (t < s2) red[t] += red[t + s2];
        __syncthreads();
    }
    const float mean = red[0] * (1.0f / 512.0f);
    __syncthreads();
    float d0 = v0 - mean, d1 = v1 - mean;
    red[t] = d0 * d0 + d1 * d1; __syncthreads();
    for (int s2 = 128; s2 > 0; s2 >>= 1) {
        if (t < s2) red[t] += red[t + s2];
        __syncthreads();
    }
    const float rs = rsqrtf(red[0] * (1.0f / 512.0f) + LN_EPS);
    float o0 = d0 * rs * g[t] + be[t];
    float o1 = d1 * rs * g[t + 256] + be[t + 256];
    out[base + t] = o0;
    out[base + t + 256] = o1;
    z1b[base + t] = f2us(o0);
    z1b[base + t + 256] = f2us(o1);
}

// ---------------------------------------------------------------------------
// wtrans: dst[n][k] (bf16) = src[k][n] (f32).  grid (K/64, N/64).
// ---------------------------------------------------------------------------
__global__ __launch_bounds__(256) void wtrans_kernel(const float* __restrict__ src,
                                                     u16* __restrict__ dst,
                                                     int K, int N) {
    __shared__ float sT[64][65];
    const int t = threadIdx.x;
    const int k0 = blockIdx.x * 64, n0 = blockIdx.y * 64;
    #pragma unroll
    for (int c = 0; c < 4; ++c) {
        const int r = (t >> 4) + c * 16;
        float4 v = *(const float4*)(src + (long)(k0 + r) * N + n0 + ((t & 15) << 2));
        sT[r][((t & 15) << 2) + 0] = v.x;
        sT[r][((t & 15) << 2) + 1] = v.y;
        sT[r][((t & 15) << 2) + 2] = v.z;
        sT[r][((t & 15) << 2) + 3] = v.w;
    }
    __syncthreads();
    const int n = t >> 2, kc = (t & 3) << 4;
    #pragma unroll
    for (int u = 0; u < 4; ++u) {
        ushort4 o;
        o.x = f2us(sT[kc + 4 * u + 0][n]);
        o.y = f2us(sT[kc + 4 * u + 1][n]);
        o.z = f2us(sT[kc + 4 * u + 2][n]);
        o.w = f2us(sT[kc + 4 * u + 3][n]);
        *(ushort4*)(dst + (long)(n0 + n) * K + k0 + kc + 4 * u) = o;
    }
}

// ---------------------------------------------------------------------------
// ffn1 (MFMA): Hff = relu(Z1b @ W1t^T + b1) -> bf16.
// ---------------------------------------------------------------------------
__global__ __launch_bounds__(256) void ffn1_kernel(const u16* __restrict__ A,
                                                   const u16* __restrict__ Bt,
                                                   const float* __restrict__ b1,
                                                   u16* __restrict__ C,
                                                   int m_base) {
    __shared__ u16 sA[64][72], sB[64][72];
    const int t = threadIdx.x;
    const int w = t >> 6, l = t & 63, quad = l >> 4, l16 = l & 15;
    const int mw = w * 16;
    const int m0 = m_base + blockIdx.y * 64, n0 = blockIdx.x * 64;
    const int r = t >> 2, cc = (t & 3) << 4;

    float4v acc[4];
    #pragma unroll
    for (int nt = 0; nt < 4; ++nt) acc[nt] = (float4v){0.f, 0.f, 0.f, 0.f};

    for (int kt = 0; kt < 512; kt += 64) {
        const long aoff = (long)(m0 + r) * 512 + kt + cc;
        *(uint4*)&sA[r][cc]     = *(const uint4*)(A + aoff);
        *(uint4*)&sA[r][cc + 8] = *(const uint4*)(A + aoff + 8);
        const long boff = (long)(n0 + r) * 512 + kt + cc;
        *(uint4*)&sB[r][cc]     = *(const uint4*)(Bt + boff);
        *(uint4*)&sB[r][cc + 8] = *(const uint4*)(Bt + boff + 8);
        __syncthreads();
        #pragma unroll
        for (int kc = 0; kc < 2; ++kc) {
            short8 a = *(const short8*)&sA[mw + l16][kc * 32 + quad * 8];
            #pragma unroll
            for (int nt = 0; nt < 4; ++nt) {
                short8 b = *(const short8*)&sB[nt * 16 + l16][kc * 32 + quad * 8];
                acc[nt] = __builtin_amdgcn_mfma_f32_16x16x32_bf16(a, b, acc[nt], 0, 0, 0);
            }
        }
        __syncthreads();
    }
    #pragma unroll
    for (int rr = 0; rr < 4; ++rr) {
        const int row = blockIdx.y * 64 + mw + quad * 4 + rr;  // chunk-local
        #pragma unroll
        for (int nt = 0; nt < 4; ++nt) {
            const int col = n0 + nt * 16 + l16;
            float v = acc[nt][rr] + b1[col];
            C[(long)row * 2048 + col] = f2us(fmaxf(v, 0.0f));
        }
    }
}

// ---------------------------------------------------------------------------
// ffn2 (MFMA): U = Hff @ W2t^T + b2 -> f32.
// ---------------------------------------------------------------------------
__global__ __launch_bounds__(256) void ffn2_kernel(const u16* __restrict__ A,
                                                   const u16* __restrict__ Bt,
                                                   const float* __restrict__ b2,
                                                   float* __restrict__ U) {
    __shared__ u16 sA[64][72], sB[64][72];
    const int t = threadIdx.x;
    const int w = t >> 6, l = t & 63, quad = l >> 4, l16 = l & 15;
    const int mw = w * 16;
    const int m0 = blockIdx.y * 64, n0 = blockIdx.x * 64;
    const int r = t >> 2, cc = (t & 3) << 4;

    float4v acc[4];
    #pragma unroll
    for (int nt = 0; nt < 4; ++nt) acc[nt] = (float4v){0.f, 0.f, 0.f, 0.f};

    for (int kt = 0; kt < 2048; kt += 64) {
        const long aoff = (long)(m0 + r) * 2048 + kt + cc;
        *(uint4*)&sA[r][cc]     = *(const uint4*)(A + aoff);
        *(uint4*)&sA[r][cc + 8] = *(const uint4*)(A + aoff + 8);
        const long boff = (long)(n0 + r) * 2048 + kt + cc;
        *(uint4*)&sB[r][cc]     = *(const uint4*)(Bt + boff);
        *(uint4*)&sB[r][cc + 8] = *(const uint4*)(Bt + boff + 8);
        __syncthreads();
        #pragma unroll
        for (int kc = 0; kc < 2; ++kc) {
            short8 a = *(const short8*)&sA[mw + l16][kc * 32 + quad * 8];
            #pragma unroll
            for (int nt = 0; nt < 4; ++nt) {
                short8 b = *(const short8*)&sB[nt * 16 + l16][kc * 32 + quad * 8];
                acc[nt] = __builtin_amdgcn_mfma_f32_16x16x32_bf16(a, b, acc[nt], 0, 0, 0);
            }
        }
        __syncthreads();
    }
    #pragma unroll
    for (int rr = 0; rr < 4; ++rr) {
        const int row = m0 + mw + quad * 4 + rr;
        #pragma unroll
        for (int nt = 0; nt < 4; ++nt) {
            const int col = n0 + nt * 16 + l16;
            U[(long)row * 512 + col] = acc[nt][rr] + b2[col];
        }
    }
}

// ---------------------------------------------------------------------------
// ln2: out = LN(U + Z1)*g + be (in place over Z1 rows).
// ---------------------------------------------------------------------------
__global__ __launch_bounds__(256) void ln2_kernel(const float* __restrict__ U,
                                                  const float* __restrict__ Z1,
                                                  const float* __restrict__ g,
                                                  const float* __restrict__ be,
                                                  float* __restrict__ out) {
    const int r = blockIdx.x, t = threadIdx.x;
    const long base = (long)r * 512;
    __shared__ float red[256];

    float v0 = U[base + t] + Z1[base + t];
    float v1 = U[base + t + 256] + Z1[base + t + 256];

    red[t] = v0 + v1; __syncthreads();
    for (int s2 = 128; s2 > 0; s2 >>= 1) {
        if (t < s2) red[t] += red[t + s2];
        __syncthreads();
    }
    const float mean = red[0] * (1.0f / 512.0f);
    __syncthreads();
    float d0 = v0 - mean, d1 = v1 - mean;
    red[t] = d0 * d0 + d1 * d1; __syncthreads();
    for (int s2 = 128; s2 > 0; s2 >>= 1) {
        if (t < s2) red[t] += red[t + s2];
        __syncthreads();
    }
    const float rs = rsqrtf(red[0] * (1.0f / 512.0f) + LN_EPS);
    out[base + t] = d0 * rs * g[t] + be[t];
    out[base + t + 256] = d1 * rs * g[t + 256] + be[t + 256];
}

// ---------------------------------------------------------------------------
// ws timeline (max 14 MB):
//   attention: Khi @0 (4) | Klo @4 (4) | Vt @8 (4)
//   wo/ln1:    tmp @0 (8) | Z1b @8 (4)
//   FFN:       W1t @0 (2) | W2t @2 (2) | Hff @4 (4/chunk) | U @12 (2/chunk)
// d_out: Qcat -> Zcat -> Z1 -> out (race-free phase overwrites).
// ---------------------------------------------------------------------------
extern "C" void kernel_launch(void* const* d_in, const int* in_sizes, int n_in,
                              void* d_out, int out_size, void* d_ws, size_t ws_size,
                              hipStream_t stream) {
    float* outf = (float*)d_out;

    static const int exp_sizes[13] = {2097152, 262144, 262144, 262144, 262144,
                                      1048576, 2048, 1048576, 512, 512, 512,
                                      512, 512};
    bool ok = (n_in == 13) && (out_size == 2097152) &&
              (ws_size >= (14ull << 20));
    if (ok) for (int i = 0; i < 13; ++i) if (in_sizes[i] != exp_sizes[i]) ok = false;
    if (!ok) { sentinel_kernel<<<16, 256, 0, stream>>>(outf, 1000.0f); return; }

    const float* E   = (const float*)d_in[0];
    const float* Wq  = (const float*)d_in[1];
    const float* Wk  = (const float*)d_in[2];
    const float* Wv  = (const float*)d_in[3];
    const float* WO  = (const float*)d_in[4];
    const float* W1  = (const float*)d_in[5];
    const float* b1  = (const float*)d_in[6];
    const float* W2  = (const float*)d_in[7];
    const float* b2  = (const float*)d_in[8];
    const float* g1  = (const float*)d_in[9];
    const float* be1 = (const float*)d_in[10];
    const float* g2  = (const float*)d_in[11];
    const float* be2 = (const float*)d_in[12];

    char* base = (char*)d_ws;
    u16*   Khi = (u16*)base;                    // 4 MB
    u16*   Klo = (u16*)(base + (4l << 20));     // 4 MB
    u16*   Vt  = (u16*)(base + (8l << 20));     // 4 MB
    float* tmp = (float*)base;                  // 8 MB (K dead)
    u16*   Z1b = (u16*)(base + (8l << 20));     // 4 MB (Vt dead)
    u16*   W1t = (u16*)base;                    // 2 MB (tmp dead)
    u16*   W2t = (u16*)(base + (2l << 20));     // 2 MB
    u16*   Hff = (u16*)(base + (4l << 20));     // 4 MB / chunk
    float* U   = (float*)(base + (12l << 20));  // 2 MB / chunk

    qkv9_kernel<<<dim3(64, 24), 256, 0, stream>>>(E, Wq, Wk, Wv, outf,
                                                  Khi, Klo, Vt);
    flash9_kernel<<<dim3(64, 8), 256, 0, stream>>>(Khi, Klo, Vt, outf);
    wo2_kernel<<<dim3(8, 64), 256, 0, stream>>>(outf, WO, tmp);
    ln1_kernel<<<4096, 256, 0, stream>>>(tmp, E, g1, be1, outf, Z1b);
    wtrans_kernel<<<dim3(8, 32), 256, 0, stream>>>(W1, W1t, 512, 2048);
    wtrans_kernel<<<dim3(32, 8), 256, 0, stream>>>(W2, W2t, 2048, 512);

    for (int c = 0; c < 4; ++c) {
        ffn1_kernel<<<dim3(32, 16), 256, 0, stream>>>(Z1b, W1t, b1, Hff,
                                                      c * 1024);
        ffn2_kernel<<<dim3(8, 16), 256, 0, stream>>>(Hff, W2t, b2, U);
        ln2_kernel<<<1024, 256, 0, stream>>>(U, outf + (long)c * 1024 * 512,
                                             g2, be2,
                                             outf + (long)c * 1024 * 512);
    }
}